// Round 1
// baseline (807.143 us; speedup 1.0000x reference)
//
#include <hip/hip_runtime.h>

#define BB 2048
#define TT 512
#define INDIM 6
#define HH 32
#define OUTD 64

__device__ __forceinline__ float sigm(float x) { return 1.f / (1.f + __expf(-x)); }

__global__ __launch_bounds__(64, 2) void lstm2_fused_kernel(
    const float* __restrict__ imu,
    const float* __restrict__ w_ih0, const float* __restrict__ w_hh0,
    const float* __restrict__ b_ih0, const float* __restrict__ b_hh0,
    const float* __restrict__ w_ih1, const float* __restrict__ w_hh1,
    const float* __restrict__ b_ih1, const float* __restrict__ b_hh1,
    const float* __restrict__ wf, const float* __restrict__ bf,
    const float* __restrict__ wn, const float* __restrict__ bn,
    float* __restrict__ out)
{
    const int b = blockIdx.x;
    const int lane = threadIdx.x;

    __shared__ __align__(16) float simu[TT * INDIM];
    __shared__ __align__(16) float hb1[HH];
    __shared__ __align__(16) float hb2[HH];

    // ---- stage this batch's imu sequence into LDS (3072 floats = 768 float4)
    {
        const float4* gi4 = (const float4*)(imu + (size_t)b * TT * INDIM);
        float4* si4 = (float4*)simu;
        #pragma unroll
        for (int i = 0; i < (TT * INDIM / 4) / 64; ++i)
            si4[lane + 64 * i] = gi4[lane + 64 * i];
    }

    // ---- per-lane gate ownership: gates gA=lane, gB=lane+64
    // gate index semantics: [0..31]=i, [32..63]=f, [64..95]=g, [96..127]=o
    const int gA = lane;
    const int gB = lane + 64;

    float wA0[INDIM], wB0[INDIM];
    #pragma unroll
    for (int i = 0; i < INDIM; ++i) {
        wA0[i] = w_ih0[gA * INDIM + i];
        wB0[i] = w_ih0[gB * INDIM + i];
    }
    float4 wA1[8], wB1[8], wA2i[8], wA2h[8], wB2i[8], wB2h[8];
    {
        const float4* wh0 = (const float4*)w_hh0;
        const float4* wi1 = (const float4*)w_ih1;
        const float4* wh1 = (const float4*)w_hh1;
        #pragma unroll
        for (int k = 0; k < 8; ++k) {
            wA1[k]  = wh0[gA * 8 + k];
            wB1[k]  = wh0[gB * 8 + k];
            wA2i[k] = wi1[gA * 8 + k];
            wB2i[k] = wi1[gB * 8 + k];
            wA2h[k] = wh1[gA * 8 + k];
            wB2h[k] = wh1[gB * 8 + k];
        }
    }
    const float bA1 = b_ih0[gA] + b_hh0[gA];
    const float bB1 = b_ih0[gB] + b_hh0[gB];
    const float bA2 = b_ih1[gA] + b_hh1[gA];
    const float bB2 = b_ih1[gB] + b_hh1[gB];

    hb1[lane & 31] = 0.f;
    hb2[lane & 31] = 0.f;
    float c1 = 0.f, c2 = 0.f;
    __syncthreads();

    const bool lo = (lane < 32);
    const float4* h1v = (const float4*)hb1;
    const float4* h2v = (const float4*)hb2;

    for (int t = 0; t < TT; ++t) {
        // ================= layer 1 =================
        float accA = bA1, accB = bB1;
        {
            const float* xt = simu + t * INDIM;
            float2 x01 = *(const float2*)(xt);
            float2 x23 = *(const float2*)(xt + 2);
            float2 x45 = *(const float2*)(xt + 4);
            accA += wA0[0] * x01.x + wA0[1] * x01.y + wA0[2] * x23.x
                  + wA0[3] * x23.y + wA0[4] * x45.x + wA0[5] * x45.y;
            accB += wB0[0] * x01.x + wB0[1] * x01.y + wB0[2] * x23.x
                  + wB0[3] * x23.y + wB0[4] * x45.x + wB0[5] * x45.y;
        }
        #pragma unroll
        for (int k = 0; k < 8; ++k) {
            float4 hv = h1v[k];
            accA += wA1[k].x * hv.x + wA1[k].y * hv.y + wA1[k].z * hv.z + wA1[k].w * hv.w;
            accB += wB1[k].x * hv.x + wB1[k].y * hv.y + wB1[k].z * hv.z + wB1[k].w * hv.w;
        }
        // activation before exchange: accA is i (lo) or f (hi) -> sigmoid.
        // accB is g (lo, tanh) or o (hi, sigmoid). tanh(x) = 2*sigm(2x)-1.
        float sA = sigm(accA);
        float sB = sigm(lo ? 2.f * accB : accB);
        float aB = lo ? 2.f * sB - 1.f : sB;
        float oA = __shfl_xor(sA, 32);
        float oB = __shfl_xor(aB, 32);
        float ig = lo ? sA : oA;
        float fg = lo ? oA : sA;
        float gg = lo ? aB : oB;
        float og = lo ? oB : aB;
        c1 = fg * c1 + ig * gg;
        float th1 = 2.f * sigm(2.f * c1) - 1.f;
        float h1n = og * th1;
        hb1[lane & 31] = h1n;   // pair lanes write identical value
        __syncthreads();

        // ================= layer 2 =================
        float accA2 = bA2, accB2 = bB2;
        #pragma unroll
        for (int k = 0; k < 8; ++k) {
            float4 av = h1v[k];
            float4 bv = h2v[k];
            accA2 += wA2i[k].x * av.x + wA2i[k].y * av.y + wA2i[k].z * av.z + wA2i[k].w * av.w;
            accA2 += wA2h[k].x * bv.x + wA2h[k].y * bv.y + wA2h[k].z * bv.z + wA2h[k].w * bv.w;
            accB2 += wB2i[k].x * av.x + wB2i[k].y * av.y + wB2i[k].z * av.z + wB2i[k].w * av.w;
            accB2 += wB2h[k].x * bv.x + wB2h[k].y * bv.y + wB2h[k].z * bv.z + wB2h[k].w * bv.w;
        }
        float sA2 = sigm(accA2);
        float sB2 = sigm(lo ? 2.f * accB2 : accB2);
        float aB2 = lo ? 2.f * sB2 - 1.f : sB2;
        float oA2 = __shfl_xor(sA2, 32);
        float oB2 = __shfl_xor(aB2, 32);
        float ig2 = lo ? sA2 : oA2;
        float fg2 = lo ? oA2 : sA2;
        float gg2 = lo ? aB2 : oB2;
        float og2 = lo ? oB2 : aB2;
        c2 = fg2 * c2 + ig2 * gg2;
        float th2 = 2.f * sigm(2.f * c2) - 1.f;
        float h2n = og2 * th2;
        hb2[lane & 31] = h2n;
        __syncthreads();
    }

    // ================= heads =================
    float accF = bf[lane];
    float accN = bn[lane];
    {
        const float4* wf4 = (const float4*)(wf + lane * HH);
        const float4* wn4 = (const float4*)(wn + lane * HH);
        #pragma unroll
        for (int k = 0; k < 8; ++k) {
            float4 hv = h2v[k];
            float4 f4 = wf4[k];
            float4 n4 = wn4[k];
            accF += f4.x * hv.x + f4.y * hv.y + f4.z * hv.z + f4.w * hv.w;
            accN += n4.x * hv.x + n4.y * hv.y + n4.z * hv.z + n4.w * hv.w;
        }
    }
    out[(size_t)b * OUTD + lane] = accF;
    out[(size_t)BB * OUTD + (size_t)b * OUTD + lane] = __expf(accN);
}

extern "C" void kernel_launch(void* const* d_in, const int* in_sizes, int n_in,
                              void* d_out, int out_size, void* d_ws, size_t ws_size,
                              hipStream_t stream) {
    const float* imu   = (const float*)d_in[0];
    const float* w_ih0 = (const float*)d_in[1];
    const float* w_hh0 = (const float*)d_in[2];
    const float* b_ih0 = (const float*)d_in[3];
    const float* b_hh0 = (const float*)d_in[4];
    const float* w_ih1 = (const float*)d_in[5];
    const float* w_hh1 = (const float*)d_in[6];
    const float* b_ih1 = (const float*)d_in[7];
    const float* b_hh1 = (const float*)d_in[8];
    const float* wf    = (const float*)d_in[9];
    const float* bf    = (const float*)d_in[10];
    const float* wn    = (const float*)d_in[11];
    const float* bn    = (const float*)d_in[12];
    float* out = (float*)d_out;

    lstm2_fused_kernel<<<dim3(BB), dim3(64), 0, stream>>>(
        imu, w_ih0, w_hh0, b_ih0, b_hh0,
        w_ih1, w_hh1, b_ih1, b_hh1,
        wf, bf, wn, bn, out);
}